// Round 7
// baseline (311.538 us; speedup 1.0000x reference)
//
#include <hip/hip_runtime.h>
#include <math.h>

#define B_   4
#define S_   2048
#define H_   1024
#define NH   16
#define HD   64
#define T_   (B_ * S_)       // 8192 tokens
#define NCH  16              // kv S-chunks

// prologue block partition
#define PB_CVT   T_                    // 8192 blocks: hs->bf16 + gate
#define PB_PACK  1024                  // weight transpose (4 x 16 x 16 tiles)
#define PB_ROPE  256                   // rope tables (65536 elems)
#define PB_MISC  13                    // bias 3072 + coeff
#define PB_ZERO  260                   // zero kvb+ksum (266240 floats, x4/thread)

typedef unsigned short u16;
typedef __bf16 bf16x8 __attribute__((ext_vector_type(8)));
typedef float  f32x4  __attribute__((ext_vector_type(4)));

// ---------------------------------------------------------------------------
__device__ __forceinline__ float elu_k(float x) {
    return (x > 0.f ? x : (expf(x) - 1.f)) + 1.000001f;
}

__device__ __forceinline__ u16 f2bf(float x) {
    union { float f; unsigned int u; } v; v.f = x;
    unsigned int r = v.u + 0x7FFFu + ((v.u >> 16) & 1u);
    return (u16)(r >> 16);
}

__device__ __forceinline__ float bfl(unsigned int u) {
    union { unsigned int u; float f; } v; v.u = u << 16; return v.f;
}
__device__ __forceinline__ float bfh(unsigned int u) {
    union { unsigned int u; float f; } v; v.u = u & 0xFFFF0000u; return v.f;
}

// async global->LDS, 16 B/lane; LDS side is wave-uniform base + lane*16.
__device__ __forceinline__ void async_load16(const u16* g, u16* l) {
    __builtin_amdgcn_global_load_lds(
        (const __attribute__((address_space(1))) void*)g,
        (__attribute__((address_space(3))) void*)l,
        16, 0, 0);
}

// ---------------------------------------------------------------------------
// Mega-prologue: blockIdx-partitioned sections (see PB_* above).
__global__ __launch_bounds__(256) void prologue_kernel(
    const float* __restrict__ hs, const float* __restrict__ Wg,
    const float* __restrict__ bg, u16* __restrict__ hsb,
    float* __restrict__ gbuf,
    const float* __restrict__ Wq, const float* __restrict__ Wk,
    const float* __restrict__ Wv, const float* __restrict__ Wo,
    u16* __restrict__ Wt,
    const float* __restrict__ decay, const float* __restrict__ gate,
    float* __restrict__ coeff, float* __restrict__ cosT,
    float* __restrict__ sinT, const float* __restrict__ bq,
    const float* __restrict__ bk, const float* __restrict__ bv,
    float* __restrict__ bqkv, float* __restrict__ zbase) {
    __shared__ u16 tile[64][65];
    __shared__ float wsum[4];
    int bi = blockIdx.x;
    int tid = threadIdx.x;

    if (bi < PB_CVT) {
        // ---- hs -> bf16 + gate gemv (one block per token)
        int t = bi;
        float4 f = ((const float4*)(hs + (size_t)t * H_))[tid];
        float4 w = ((const float4*)Wg)[tid];
        ushort4 u;
        u.x = f2bf(f.x); u.y = f2bf(f.y); u.z = f2bf(f.z); u.w = f2bf(f.w);
        ((ushort4*)(hsb + (size_t)t * H_))[tid] = u;
        float s = f.x * w.x + f.y * w.y + f.z * w.z + f.w * w.w;
#pragma unroll
        for (int off = 32; off > 0; off >>= 1) s += __shfl_down(s, off);
        if ((tid & 63) == 0) wsum[tid >> 6] = s;
        __syncthreads();
        if (tid == 0) {
            float tot = wsum[0] + wsum[1] + wsum[2] + wsum[3];
            gbuf[t] = 1.f / (1.f + expf(-(tot + bg[0])));
        }
        return;
    }
    bi -= PB_CVT;
    if (bi < PB_PACK) {
        // ---- weight transpose+convert: Wt[w*1024 + n][k] = bf16(W_w[k][n])
        int wsel = bi >> 8;
        int kt = ((bi >> 4) & 15) * 64, nt = (bi & 15) * 64;
        const float* W = (wsel == 0) ? Wq : (wsel == 1) ? Wk :
                         (wsel == 2) ? Wv : Wo;
#pragma unroll
        for (int it = 0; it < 16; it++) {
            int i = it * 256 + tid;
            int kr = i >> 6, nc = i & 63;
            tile[kr][nc] = f2bf(W[(size_t)(kt + kr) * H_ + nt + nc]);
        }
        __syncthreads();
        size_t wbase = (size_t)wsel * H_;
#pragma unroll
        for (int it = 0; it < 16; it++) {
            int i = it * 256 + tid;
            int nr = i >> 6, kc = i & 63;
            Wt[(wbase + nt + nr) * H_ + kt + kc] = tile[kc][nr];
        }
        return;
    }
    bi -= PB_PACK;
    if (bi < PB_ROPE) {
        int idx = bi * 256 + tid;          // < 65536
        int s = idx >> 5, i = idx & 31;
        float inv = powf(10000.f, -(2.f * (float)i) / 64.f);
        float f = (float)s * inv;
        cosT[idx] = cosf(f);
        sinT[idx] = sinf(f);
        return;
    }
    bi -= PB_ROPE;
    if (bi < PB_MISC) {
        int i = bi * 256 + tid;
        if (i < 3072) {
            bqkv[i] = (i < 1024) ? bq[i] : (i < 2048) ? bk[i - 1024]
                                                      : bv[i - 2048];
        } else if (i == 3072) {
            float g0 = gate[0], g1 = gate[1], g2 = gate[2];
            float mx = fmaxf(g0, fmaxf(g1, g2));
            float e0 = expf(g0 - mx), e1 = expf(g1 - mx), e2 = expf(g2 - mx);
            float inv = 1.f / (e0 + e1 + e2);
            float es[3] = {e0, e1, e2};
            float c = 0.f;
            for (int m = 0; m < 3; m++) {
                float ds = 1.f / (1.f + expf(-decay[m]));
                c += es[m] * inv * (1.f - ds);
            }
            *coeff = c;
        }
        return;
    }
    bi -= PB_MISC;
    // ---- zero kvb + ksum (266240 floats)
    int i = bi * 256 + tid;
    if (i < 66560) ((float4*)zbase)[i] = {0.f, 0.f, 0.f, 0.f};
}

// ---------------------------------------------------------------------------
// GEMM K-loop: BK=64 staged as two BK=32 half-tiles, m97 bank-clean layout
// (row stride 32 u16). 8 async insts/lane/iter, 32 MFMAs/iter, 16 iters.
#define GEMM_KLOOP(A_, Bt_, bm_, bn_)                                         \
    for (int k0 = 0; k0 < K; k0 += 64) {                                      \
        _Pragma("unroll")                                                     \
        for (int h = 0; h < 2; h++) {                                         \
            _Pragma("unroll")                                                 \
            for (int i = 0; i < 2; i++) {                                     \
                int r0 = (wave * 2 + i) * 16;                                 \
                int rr = lane >> 2, cc = lane & 3;                            \
                async_load16(&A_[(size_t)(bm_ + r0 + rr) * K + k0 + h * 32 + cc * 8], \
                             &Asl[h][r0 * 32]);                               \
                async_load16(&Bt_[(size_t)(bn_ + r0 + rr) * K + k0 + h * 32 + cc * 8], \
                             &Bsl[h][r0 * 32]);                               \
            }                                                                 \
        }                                                                     \
        asm volatile("s_waitcnt vmcnt(0)" ::: "memory");                      \
        __syncthreads();                                                      \
        _Pragma("unroll")                                                     \
        for (int h = 0; h < 2; h++) {                                         \
            bf16x8 af[4], bfr[4];                                             \
            _Pragma("unroll")                                                 \
            for (int mi = 0; mi < 4; mi++)                                    \
                af[mi] = *(const bf16x8*)&Asl[h][(wm + mi * 16 + l15) * 32 + quad * 8]; \
            _Pragma("unroll")                                                 \
            for (int nj = 0; nj < 4; nj++)                                    \
                bfr[nj] = *(const bf16x8*)&Bsl[h][(wn + nj * 16 + l15) * 32 + quad * 8]; \
            _Pragma("unroll")                                                 \
            for (int mi = 0; mi < 4; mi++)                                    \
                _Pragma("unroll")                                             \
                for (int nj = 0; nj < 4; nj++)                                \
                    acc[mi][nj] = __builtin_amdgcn_mfma_f32_16x16x32_bf16(    \
                        af[mi], bfr[nj], acc[mi][nj], 0, 0, 0);               \
        }                                                                     \
        __syncthreads();                                                      \
    }

// ---------------------------------------------------------------------------
// QKV GEMM with fused rope+elu+mask epilogue -> bf16 head-major qb/kb/vb.
__global__ __launch_bounds__(256) void gemm_qkv_kernel(
    const u16* __restrict__ A, const u16* __restrict__ Bt,
    const float* __restrict__ bias, const float* __restrict__ mask,
    const float* __restrict__ cosT, const float* __restrict__ sinT,
    u16* __restrict__ qb, u16* __restrict__ kb, u16* __restrict__ vb) {
    constexpr int K = 1024;
    __shared__ u16 Asl[2][128 * 32];
    __shared__ u16 Bsl[2][128 * 32];
    const int tid  = threadIdx.x;
    const int wave = tid >> 6, lane = tid & 63;
    const int wm = (wave & 1) * 64, wn = (wave >> 1) * 64;
    const int bm = blockIdx.y * 128, bn = blockIdx.x * 128;
    const int l15 = lane & 15, quad = lane >> 4;

    f32x4 acc[4][4];
#pragma unroll
    for (int i = 0; i < 4; i++)
#pragma unroll
        for (int j = 0; j < 4; j++) acc[i][j] = {0.f, 0.f, 0.f, 0.f};

    GEMM_KLOOP(A, Bt, bm, bn)

    // ---- fused epilogue
    const int colbase = bn + wn;              // multiple of 64
    const int region  = colbase >> 10;        // 0=q 1=k 2=v
    const int n       = (colbase & 1023) >> 6;
    float bc[4];
#pragma unroll
    for (int nj = 0; nj < 4; nj++) bc[nj] = bias[colbase + nj * 16 + l15];
    u16* outp = (region == 0) ? qb : (region == 1) ? kb : vb;

#pragma unroll
    for (int mi = 0; mi < 4; mi++) {
#pragma unroll
        for (int r = 0; r < 4; r++) {
            int row = bm + wm + mi * 16 + quad * 4 + r;
            int b = row >> 11, s = row & (S_ - 1);
            size_t obase = ((size_t)(b * 16 + n) * S_ + s) * 64;
            if (region < 2) {
                float mfac = (region == 0) ? 0.125f : mask[row];
#pragma unroll
                for (int p = 0; p < 2; p++) {
                    int d1 = p * 16 + l15;
                    float c  = cosT[s * 32 + d1];
                    float sn = sinT[s * 32 + d1];
                    float x1 = acc[mi][p][r]     + bc[p];
                    float x2 = acc[mi][p + 2][r] + bc[p + 2];
                    float r1 = x1 * c - x2 * sn;
                    float r2 = x2 * c + x1 * sn;
                    outp[obase + d1]      = f2bf(elu_k(r1) * mfac);
                    outp[obase + d1 + 32] = f2bf(elu_k(r2) * mfac);
                }
            } else {
                float mfac = mask[row];
#pragma unroll
                for (int nj = 0; nj < 4; nj++)
                    outp[obase + nj * 16 + l15] =
                        f2bf((acc[mi][nj][r] + bc[nj]) * mfac);
            }
        }
    }
}

// ---------------------------------------------------------------------------
// Output projection GEMM: C fp32 = A @ Bt^T + bias. Grid (8, 64).
__global__ __launch_bounds__(256) void gemm_out_kernel(
    const u16* __restrict__ A, const u16* __restrict__ Bt,
    const float* __restrict__ bias, float* __restrict__ C, int N) {
    constexpr int K = 1024;
    __shared__ u16 Asl[2][128 * 32];
    __shared__ u16 Bsl[2][128 * 32];
    const int tid  = threadIdx.x;
    const int wave = tid >> 6, lane = tid & 63;
    const int wm = (wave & 1) * 64, wn = (wave >> 1) * 64;
    const int bm = blockIdx.y * 128, bn = blockIdx.x * 128;
    const int l15 = lane & 15, quad = lane >> 4;

    f32x4 acc[4][4];
#pragma unroll
    for (int i = 0; i < 4; i++)
#pragma unroll
        for (int j = 0; j < 4; j++) acc[i][j] = {0.f, 0.f, 0.f, 0.f};

    GEMM_KLOOP(A, Bt, bm, bn)

#pragma unroll
    for (int mi = 0; mi < 4; mi++) {
#pragma unroll
        for (int nj = 0; nj < 4; nj++) {
            int col = bn + wn + nj * 16 + l15;
            float bcol = bias[col];
#pragma unroll
            for (int r = 0; r < 4; r++) {
                int row = bm + wm + mi * 16 + quad * 4 + r;
                C[(size_t)row * N + col] = acc[mi][nj][r] + bcol;
            }
        }
    }
}

// ---------------------------------------------------------------------------
// kv partials: grid (64 bn, NCH); atomicAdd finalize into zeroed kvb/ksum
// (zeroed by prologue, stream-ordered 2 dispatches earlier).
__global__ __launch_bounds__(256) void kv_part_kernel(
    const u16* __restrict__ kb, const u16* __restrict__ vb,
    float* __restrict__ kvb, float* __restrict__ ksum) {
    int bn = blockIdx.x;
    const int rows = S_ / NCH;              // 128
    int s0 = blockIdx.y * rows;
    int tid = threadIdx.x;
    int ti = tid >> 4, tj = tid & 15;
    __shared__ float ks[16][64], vs[16][64];
    float acc[4][4] = {};
    float ksacc = 0.f;
    const u16* kbase = kb + (size_t)bn * (S_ * 64) + (size_t)s0 * 64;
    const u16* vbase = vb + (size_t)bn * (S_ * 64) + (size_t)s0 * 64;
    for (int ss = 0; ss < rows; ss += 16) {
        {
            int half = tid >> 7;
            int c = tid & 127;
            int rr = c >> 3, col = (c & 7) * 8;
            const u16* src = (half ? vbase : kbase) + (size_t)(ss + rr) * 64 + col;
            uint4 raw = *(const uint4*)src;
            float* dst = half ? &vs[rr][col] : &ks[rr][col];
            dst[0] = bfl(raw.x); dst[1] = bfh(raw.x);
            dst[2] = bfl(raw.y); dst[3] = bfh(raw.y);
            dst[4] = bfl(raw.z); dst[5] = bfh(raw.z);
            dst[6] = bfl(raw.w); dst[7] = bfh(raw.w);
        }
        __syncthreads();
#pragma unroll
        for (int r = 0; r < 16; r++) {
            float a[4], bb[4];
#pragma unroll
            for (int i = 0; i < 4; i++) a[i] = ks[r][ti * 4 + i];
#pragma unroll
            for (int j = 0; j < 4; j++) bb[j] = vs[r][tj * 4 + j];
#pragma unroll
            for (int i = 0; i < 4; i++)
#pragma unroll
                for (int j = 0; j < 4; j++)
                    acc[i][j] = fmaf(a[i], bb[j], acc[i][j]);
        }
        if (tid < 64) {
#pragma unroll
            for (int r = 0; r < 16; r++) ksacc += ks[r][tid];
        }
        __syncthreads();
    }
#pragma unroll
    for (int i = 0; i < 4; i++)
#pragma unroll
        for (int j = 0; j < 4; j++)
            atomicAdd(&kvb[(size_t)bn * 4096 + (size_t)(ti * 4 + i) * 64 + tj * 4 + j],
                      acc[i][j]);
    if (tid < 64) atomicAdd(&ksum[bn * 64 + tid], ksacc);
}

// ---------------------------------------------------------------------------
// MFMA combine: per (b,n), num = Q[256x64] @ kv[64x64], den via ksum column.
__global__ __launch_bounds__(256) void combine_kernel(
    const u16* __restrict__ qb, const float* __restrict__ kvb,
    const float* __restrict__ ksum, const float* __restrict__ g,
    const float* __restrict__ coeffp, u16* __restrict__ cmb) {
    int bn = blockIdx.x;
    int b = bn >> 4, n = bn & 15;
    __shared__ u16 qs[256 * 72];
    __shared__ u16 kvT[64 * 72];
    __shared__ u16 ksl[128];
    int tid = threadIdx.x;
    int s0 = blockIdx.y * 256;

    const u16* qsrc = qb + (size_t)bn * (S_ * 64) + (size_t)s0 * 64;
    for (int c = tid; c < 2048; c += 256) {
        int t = c >> 3, k8 = (c & 7) * 8;
        float4 tmp = *(const float4*)(qsrc + (size_t)c * 8);
        *(float4*)&qs[t * 72 + k8] = tmp;
    }
    for (int c = tid; c < 1024; c += 256) {
        int i = c >> 4, d4 = (c & 15) * 4;
        float4 kvv = *(const float4*)&kvb[(size_t)bn * 4096 + i * 64 + d4];
        kvT[(d4 + 0) * 72 + i] = f2bf(kvv.x);
        kvT[(d4 + 1) * 72 + i] = f2bf(kvv.y);
        kvT[(d4 + 2) * 72 + i] = f2bf(kvv.z);
        kvT[(d4 + 3) * 72 + i] = f2bf(kvv.w);
    }
    if (tid < 64)        ksl[tid] = f2bf(ksum[bn * 64 + tid]);
    else if (tid < 128)  ksl[tid] = 0;
    __syncthreads();

    int wave = tid >> 6, lane = tid & 63;
    int l15 = lane & 15, quad = lane >> 4;
    int wt = wave * 64;

    int ko0 = (l15 == 0) ? quad * 8      : 64;
    int ko1 = (l15 == 0) ? 32 + quad * 8 : 64;
    bf16x8 ksf0 = *(const bf16x8*)&ksl[ko0];
    bf16x8 ksf1 = *(const bf16x8*)&ksl[ko1];

    bf16x8 bfr0[4], bfr1[4];
#pragma unroll
    for (int nj = 0; nj < 4; nj++) {
        bfr0[nj] = *(const bf16x8*)&kvT[(nj * 16 + l15) * 72 + quad * 8];
        bfr1[nj] = *(const bf16x8*)&kvT[(nj * 16 + l15) * 72 + 32 + quad * 8];
    }

    f32x4 acc[4][4], dacc[4];
#pragma unroll
    for (int i = 0; i < 4; i++) {
        dacc[i] = {0.f, 0.f, 0.f, 0.f};
#pragma unroll
        for (int j = 0; j < 4; j++) acc[i][j] = {0.f, 0.f, 0.f, 0.f};
    }

#pragma unroll
    for (int mi = 0; mi < 4; mi++) {
        bf16x8 a0 = *(const bf16x8*)&qs[(wt + mi * 16 + l15) * 72 + quad * 8];
        bf16x8 a1 = *(const bf16x8*)&qs[(wt + mi * 16 + l15) * 72 + 32 + quad * 8];
        dacc[mi] = __builtin_amdgcn_mfma_f32_16x16x32_bf16(a0, ksf0, dacc[mi], 0, 0, 0);
        dacc[mi] = __builtin_amdgcn_mfma_f32_16x16x32_bf16(a1, ksf1, dacc[mi], 0, 0, 0);
#pragma unroll
        for (int nj = 0; nj < 4; nj++) {
            acc[mi][nj] = __builtin_amdgcn_mfma_f32_16x16x32_bf16(
                a0, bfr0[nj], acc[mi][nj], 0, 0, 0);
            acc[mi][nj] = __builtin_amdgcn_mfma_f32_16x16x32_bf16(
                a1, bfr1[nj], acc[mi][nj], 0, 0, 0);
        }
    }

    float coeff = *coeffp;
#pragma unroll
    for (int mi = 0; mi < 4; mi++) {
#pragma unroll
        for (int r = 0; r < 4; r++) {
            int s = s0 + wt + mi * 16 + quad * 4 + r;
            int t = b * S_ + s;
            float den = __shfl(dacc[mi][r], lane & 48) + 1e-6f;
            float gv = g[t];
            float w1 = gv / den + (1.f - gv) * coeff;
#pragma unroll
            for (int nj = 0; nj < 4; nj++) {
                int d = nj * 16 + l15;
                cmb[(size_t)t * H_ + n * 64 + d] = f2bf(acc[mi][nj][r] * w1);
            }
        }
    }
}

// ---------------------------------------------------------------------------
extern "C" void kernel_launch(void* const* d_in, const int* in_sizes, int n_in,
                              void* d_out, int out_size, void* d_ws, size_t ws_size,
                              hipStream_t stream) {
    const float* hs    = (const float*)d_in[0];
    const float* mask  = (const float*)d_in[1];
    const float* Wq    = (const float*)d_in[2];
    const float* bq    = (const float*)d_in[3];
    const float* Wk    = (const float*)d_in[4];
    const float* bk    = (const float*)d_in[5];
    const float* Wv    = (const float*)d_in[6];
    const float* bv    = (const float*)d_in[7];
    const float* Wo    = (const float*)d_in[8];
    const float* bo    = (const float*)d_in[9];
    const float* Wg    = (const float*)d_in[10];
    const float* bg    = (const float*)d_in[11];
    const float* decay = (const float*)d_in[12];
    const float* gate  = (const float*)d_in[13];
    float* out = (float*)d_out;

    // ---- workspace layout
    float* ws     = (float*)d_ws;
    float* kvb    = ws;                         // 262144   (zeroed by prologue)
    float* ksum   = kvb + 262144;               // 4096     (zeroed by prologue)
    float* gbuf   = ksum + 4096;                // 8192
    float* coeff  = gbuf + 8192;                // 64
    float* cosT   = coeff + 64;                 // 65536
    float* sinT   = cosT + 65536;               // 65536
    float* bqkv   = sinT + 65536;               // 3072 (+pad to 4096)
    u16*   hsb    = (u16*)(bqkv + 4096);        // T*1024
    u16*   Wt     = hsb + (size_t)T_ * H_;      // 4096*1024 ([Wq|Wk|Wv|Wo]^T)
    u16*   WoT    = Wt + (size_t)3072 * H_;
    u16*   qb     = Wt + (size_t)4096 * H_;     // T*1024 head-major
    u16*   kb     = qb + (size_t)T_ * H_;
    u16*   vb     = kb + (size_t)T_ * H_;
    u16*   cmb    = vb + (size_t)T_ * H_;

    const int pgrid = PB_CVT + PB_PACK + PB_ROPE + PB_MISC + PB_ZERO;  // 9745
    prologue_kernel<<<pgrid, 256, 0, stream>>>(
        hs, Wg, bg, hsb, gbuf, Wq, Wk, Wv, Wo, Wt,
        decay, gate, coeff, cosT, sinT, bq, bk, bv, bqkv, kvb);

    gemm_qkv_kernel<<<dim3(3072 / 128, T_ / 128), 256, 0, stream>>>(
        hsb, Wt, bqkv, mask, cosT, sinT, qb, kb, vb);

    kv_part_kernel<<<dim3(B_ * NH, NCH), 256, 0, stream>>>(
        kb, vb, kvb, ksum);

    combine_kernel<<<dim3(B_ * NH, S_ / 256), 256, 0, stream>>>(
        qb, kvb, ksum, gbuf, coeff, cmb);

    gemm_out_kernel<<<dim3(H_ / 128, T_ / 128), 256, 0, stream>>>(
        cmb, WoT, bo, out, H_);
}

// Round 8
// 278.052 us; speedup vs baseline: 1.1204x; 1.1204x over previous
//
#include <hip/hip_runtime.h>
#include <math.h>

#define B_   4
#define S_   2048
#define H_   1024
#define NH   16
#define HD   64
#define T_   (B_ * S_)       // 8192 tokens
#define NCH  16              // kv S-chunks

typedef unsigned short u16;
typedef __bf16 bf16x8 __attribute__((ext_vector_type(8)));
typedef float  f32x4  __attribute__((ext_vector_type(4)));

// ---------------------------------------------------------------------------
__device__ __forceinline__ float elu_k(float x) {
    return (x > 0.f ? x : (expf(x) - 1.f)) + 1.000001f;
}

__device__ __forceinline__ u16 f2bf(float x) {
    union { float f; unsigned int u; } v; v.f = x;
    unsigned int r = v.u + 0x7FFFu + ((v.u >> 16) & 1u);
    return (u16)(r >> 16);
}

__device__ __forceinline__ float bfl(unsigned int u) {
    union { unsigned int u; float f; } v; v.u = u << 16; return v.f;
}
__device__ __forceinline__ float bfh(unsigned int u) {
    union { unsigned int u; float f; } v; v.u = u & 0xFFFF0000u; return v.f;
}

// async global->LDS, 16 B/lane; LDS side is wave-uniform base + lane*16.
__device__ __forceinline__ void async_load16(const u16* g, u16* l) {
    __builtin_amdgcn_global_load_lds(
        (const __attribute__((address_space(1))) void*)g,
        (__attribute__((address_space(3))) void*)l,
        16, 0, 0);
}

// ---------------------------------------------------------------------------
// prep: rope tables + packed bias + coeff, one small launch.
__global__ __launch_bounds__(256) void prep_kernel(
    const float* __restrict__ decay, const float* __restrict__ gate,
    float* __restrict__ coeff, float* __restrict__ cosT,
    float* __restrict__ sinT, const float* __restrict__ bq,
    const float* __restrict__ bk, const float* __restrict__ bv,
    float* __restrict__ bqkv) {
    int idx = blockIdx.x * 256 + threadIdx.x;
    if (idx < S_ * 32) {
        int s = idx >> 5, i = idx & 31;
        float inv = powf(10000.f, -(2.f * (float)i) / 64.f);
        float f = (float)s * inv;
        cosT[idx] = cosf(f);
        sinT[idx] = sinf(f);
    } else if (idx < S_ * 32 + 3072) {
        int i = idx - S_ * 32;
        bqkv[i] = (i < 1024) ? bq[i] : (i < 2048) ? bk[i - 1024] : bv[i - 2048];
    } else if (idx == S_ * 32 + 3072) {
        float g0 = gate[0], g1 = gate[1], g2 = gate[2];
        float mx = fmaxf(g0, fmaxf(g1, g2));
        float e0 = expf(g0 - mx), e1 = expf(g1 - mx), e2 = expf(g2 - mx);
        float inv = 1.f / (e0 + e1 + e2);
        float es[3] = {e0, e1, e2};
        float c = 0.f;
        for (int m = 0; m < 3; m++) {
            float ds = 1.f / (1.f + expf(-decay[m]));
            c += es[m] * inv * (1.f - ds);
        }
        *coeff = c;
    }
}

// ---------------------------------------------------------------------------
// hs->bf16 + gate gemv; grid-stride: 1024 blocks x 8 tokens, Wg in registers.
__global__ __launch_bounds__(256) void cvt_gate_kernel(
    const float* __restrict__ hs, const float* __restrict__ Wg,
    const float* __restrict__ bg, u16* __restrict__ hsb,
    float* __restrict__ gbuf) {
    int tid = threadIdx.x;
    float4 w = ((const float4*)Wg)[tid];
    float bgv = bg[0];
    __shared__ float wsum[4];
    for (int tt = 0; tt < 8; tt++) {
        int t = blockIdx.x * 8 + tt;
        float4 f = ((const float4*)(hs + (size_t)t * H_))[tid];
        ushort4 u;
        u.x = f2bf(f.x); u.y = f2bf(f.y); u.z = f2bf(f.z); u.w = f2bf(f.w);
        ((ushort4*)(hsb + (size_t)t * H_))[tid] = u;
        float s = f.x * w.x + f.y * w.y + f.z * w.z + f.w * w.w;
#pragma unroll
        for (int off = 32; off > 0; off >>= 1) s += __shfl_down(s, off);
        if ((tid & 63) == 0) wsum[tid >> 6] = s;
        __syncthreads();
        if (tid == 0) {
            float tot = wsum[0] + wsum[1] + wsum[2] + wsum[3];
            gbuf[t] = 1.f / (1.f + expf(-(tot + bgv)));
        }
        __syncthreads();
    }
}

// ---------------------------------------------------------------------------
// Transpose+convert weights: Wt[w*1024 + n][k] = bf16(W_w[k][n])
// float4 reads, ushort4 writes, 64x64 tile (padded stride 68).
__global__ __launch_bounds__(256) void pack_w_kernel(
    const float* __restrict__ Wq, const float* __restrict__ Wk,
    const float* __restrict__ Wv, const float* __restrict__ Wo,
    u16* __restrict__ Wt) {
    __shared__ u16 tile[64][68];
    const float* W = (blockIdx.z == 0) ? Wq :
                     (blockIdx.z == 1) ? Wk :
                     (blockIdx.z == 2) ? Wv : Wo;
    int nt = blockIdx.x * 64, kt = blockIdx.y * 64;
    int tid = threadIdx.x;
#pragma unroll
    for (int it = 0; it < 4; it++) {
        int i = it * 256 + tid;
        int kr = i >> 4, nc4 = (i & 15) * 4;
        float4 f = *(const float4*)&W[(size_t)(kt + kr) * H_ + nt + nc4];
        tile[kr][nc4 + 0] = f2bf(f.x);
        tile[kr][nc4 + 1] = f2bf(f.y);
        tile[kr][nc4 + 2] = f2bf(f.z);
        tile[kr][nc4 + 3] = f2bf(f.w);
    }
    __syncthreads();
    size_t wbase = (size_t)blockIdx.z * H_;
#pragma unroll
    for (int it = 0; it < 4; it++) {
        int i = it * 256 + tid;
        int nr = i >> 4, kc4 = (i & 15) * 4;
        ushort4 o;
        o.x = tile[kc4 + 0][nr];
        o.y = tile[kc4 + 1][nr];
        o.z = tile[kc4 + 2][nr];
        o.w = tile[kc4 + 3][nr];
        *(ushort4*)&Wt[(wbase + nt + nr) * H_ + kt + kc4] = o;
    }
}

// ---------------------------------------------------------------------------
// GEMM K-loop: block tile 64(M)x128(N), BK=32, 4 waves 2x2, wave tile 32x64.
// 12 KB LDS -> 8 resident blocks/CU (wave-capped). Per wave/iter:
// 3 async_load16, 6 ds_read_b128, 8 MFMA.
#define GEMM_KLOOP(A_, Bt_, bm_, bn_)                                         \
    for (int k0 = 0; k0 < K; k0 += 32) {                                      \
        {                                                                     \
            int rr = lane >> 2, cc = (lane & 3) * 8;                          \
            async_load16(&A_[(size_t)(bm_ + wave * 16 + rr) * K + k0 + cc],   \
                         &Asl[(wave * 16) * 32]);                             \
            async_load16(&Bt_[(size_t)(bn_ + wave * 16 + rr) * K + k0 + cc],  \
                         &Bsl[(wave * 16) * 32]);                             \
            async_load16(&Bt_[(size_t)(bn_ + 64 + wave * 16 + rr) * K + k0 + cc], \
                         &Bsl[(64 + wave * 16) * 32]);                        \
        }                                                                     \
        asm volatile("s_waitcnt vmcnt(0)" ::: "memory");                      \
        __syncthreads();                                                      \
        bf16x8 af[2], bfr[4];                                                 \
        _Pragma("unroll")                                                     \
        for (int mi = 0; mi < 2; mi++)                                        \
            af[mi] = *(const bf16x8*)&Asl[(wm + mi * 16 + l15) * 32 + quad * 8]; \
        _Pragma("unroll")                                                     \
        for (int nj = 0; nj < 4; nj++)                                        \
            bfr[nj] = *(const bf16x8*)&Bsl[(wn + nj * 16 + l15) * 32 + quad * 8]; \
        _Pragma("unroll")                                                     \
        for (int mi = 0; mi < 2; mi++)                                        \
            _Pragma("unroll")                                                 \
            for (int nj = 0; nj < 4; nj++)                                    \
                acc[mi][nj] = __builtin_amdgcn_mfma_f32_16x16x32_bf16(        \
                    af[mi], bfr[nj], acc[mi][nj], 0, 0, 0);                   \
        __syncthreads();                                                      \
    }

// ---------------------------------------------------------------------------
// QKV GEMM with fused rope+elu+mask epilogue -> bf16 head-major qb/kb/vb.
// grid (3072/128=24, 8192/64=128) = 3072 blocks.
__global__ __launch_bounds__(256) void gemm_qkv_kernel(
    const u16* __restrict__ A, const u16* __restrict__ Bt,
    const float* __restrict__ bias, const float* __restrict__ mask,
    const float* __restrict__ cosT, const float* __restrict__ sinT,
    u16* __restrict__ qb, u16* __restrict__ kb, u16* __restrict__ vb) {
    constexpr int K = 1024;
    __shared__ u16 Asl[64 * 32];    // 4 KB
    __shared__ u16 Bsl[128 * 32];   // 8 KB
    const int tid  = threadIdx.x;
    const int wave = tid >> 6, lane = tid & 63;
    const int wm = (wave & 1) * 32, wn = (wave >> 1) * 64;
    const int bm = blockIdx.y * 64, bn = blockIdx.x * 128;
    const int l15 = lane & 15, quad = lane >> 4;

    f32x4 acc[2][4];
#pragma unroll
    for (int i = 0; i < 2; i++)
#pragma unroll
        for (int j = 0; j < 4; j++) acc[i][j] = {0.f, 0.f, 0.f, 0.f};

    GEMM_KLOOP(A, Bt, bm, bn)

    // ---- fused epilogue (wn span = 64 = exactly one head)
    const int colbase = bn + wn;              // multiple of 64
    const int region  = colbase >> 10;        // 0=q 1=k 2=v
    const int n       = (colbase & 1023) >> 6;
    float bc[4];
#pragma unroll
    for (int nj = 0; nj < 4; nj++) bc[nj] = bias[colbase + nj * 16 + l15];
    u16* outp = (region == 0) ? qb : (region == 1) ? kb : vb;

#pragma unroll
    for (int mi = 0; mi < 2; mi++) {
#pragma unroll
        for (int r = 0; r < 4; r++) {
            int row = bm + wm + mi * 16 + quad * 4 + r;
            int b = row >> 11, s = row & (S_ - 1);
            size_t obase = ((size_t)(b * 16 + n) * S_ + s) * 64;
            if (region < 2) {
                float mfac = (region == 0) ? 0.125f : mask[row];
#pragma unroll
                for (int p = 0; p < 2; p++) {
                    int d1 = p * 16 + l15;
                    float c  = cosT[s * 32 + d1];
                    float sn = sinT[s * 32 + d1];
                    float x1 = acc[mi][p][r]     + bc[p];
                    float x2 = acc[mi][p + 2][r] + bc[p + 2];
                    float r1 = x1 * c - x2 * sn;
                    float r2 = x2 * c + x1 * sn;
                    outp[obase + d1]      = f2bf(elu_k(r1) * mfac);
                    outp[obase + d1 + 32] = f2bf(elu_k(r2) * mfac);
                }
            } else {
                float mfac = mask[row];
#pragma unroll
                for (int nj = 0; nj < 4; nj++)
                    outp[obase + nj * 16 + l15] =
                        f2bf((acc[mi][nj][r] + bc[nj]) * mfac);
            }
        }
    }
}

// ---------------------------------------------------------------------------
// Output projection GEMM: C fp32 = A @ Bt^T + bias. grid (8, 128) = 1024.
__global__ __launch_bounds__(256) void gemm_out_kernel(
    const u16* __restrict__ A, const u16* __restrict__ Bt,
    const float* __restrict__ bias, float* __restrict__ C, int N) {
    constexpr int K = 1024;
    __shared__ u16 Asl[64 * 32];
    __shared__ u16 Bsl[128 * 32];
    const int tid  = threadIdx.x;
    const int wave = tid >> 6, lane = tid & 63;
    const int wm = (wave & 1) * 32, wn = (wave >> 1) * 64;
    const int bm = blockIdx.y * 64, bn = blockIdx.x * 128;
    const int l15 = lane & 15, quad = lane >> 4;

    f32x4 acc[2][4];
#pragma unroll
    for (int i = 0; i < 2; i++)
#pragma unroll
        for (int j = 0; j < 4; j++) acc[i][j] = {0.f, 0.f, 0.f, 0.f};

    GEMM_KLOOP(A, Bt, bm, bn)

#pragma unroll
    for (int mi = 0; mi < 2; mi++) {
#pragma unroll
        for (int nj = 0; nj < 4; nj++) {
            int col = bn + wn + nj * 16 + l15;
            float bcol = bias[col];
#pragma unroll
            for (int r = 0; r < 4; r++) {
                int row = bm + wm + mi * 16 + quad * 4 + r;
                C[(size_t)row * N + col] = acc[mi][nj][r] + bcol;
            }
        }
    }
}

// ---------------------------------------------------------------------------
// kv partials from bf16 head-major k,v: grid (64 bn, NCH). No atomics.
__global__ __launch_bounds__(256) void kv_part_kernel(
    const u16* __restrict__ kb, const u16* __restrict__ vb,
    float* __restrict__ kvpart, float* __restrict__ kspart) {
    int bn = blockIdx.x;
    const int rows = S_ / NCH;              // 128
    int s0 = blockIdx.y * rows;
    int tid = threadIdx.x;
    int ti = tid >> 4, tj = tid & 15;
    __shared__ float ks[16][64], vs[16][64];
    float acc[4][4] = {};
    float ksacc = 0.f;
    const u16* kbase = kb + (size_t)bn * (S_ * 64) + (size_t)s0 * 64;
    const u16* vbase = vb + (size_t)bn * (S_ * 64) + (size_t)s0 * 64;
    for (int ss = 0; ss < rows; ss += 16) {
        {
            int half = tid >> 7;
            int c = tid & 127;
            int rr = c >> 3, col = (c & 7) * 8;
            const u16* src = (half ? vbase : kbase) + (size_t)(ss + rr) * 64 + col;
            uint4 raw = *(const uint4*)src;
            float* dst = half ? &vs[rr][col] : &ks[rr][col];
            dst[0] = bfl(raw.x); dst[1] = bfh(raw.x);
            dst[2] = bfl(raw.y); dst[3] = bfh(raw.y);
            dst[4] = bfl(raw.z); dst[5] = bfh(raw.z);
            dst[6] = bfl(raw.w); dst[7] = bfh(raw.w);
        }
        __syncthreads();
#pragma unroll
        for (int r = 0; r < 16; r++) {
            float a[4], bb[4];
#pragma unroll
            for (int i = 0; i < 4; i++) a[i] = ks[r][ti * 4 + i];
#pragma unroll
            for (int j = 0; j < 4; j++) bb[j] = vs[r][tj * 4 + j];
#pragma unroll
            for (int i = 0; i < 4; i++)
#pragma unroll
                for (int j = 0; j < 4; j++)
                    acc[i][j] = fmaf(a[i], bb[j], acc[i][j]);
        }
        if (tid < 64) {
#pragma unroll
            for (int r = 0; r < 16; r++) ksacc += ks[r][tid];
        }
        __syncthreads();
    }
    size_t obase = ((size_t)blockIdx.y * 64 + bn) * 4096;
#pragma unroll
    for (int i = 0; i < 4; i++)
#pragma unroll
        for (int j = 0; j < 4; j++)
            kvpart[obase + (size_t)(ti * 4 + i) * 64 + tj * 4 + j] = acc[i][j];
    if (tid < 64)
        kspart[((size_t)blockIdx.y * 64 + bn) * 64 + tid] = ksacc;
}

// sum NCH partials for kv (262144) and ksum (4096) in one launch
__global__ __launch_bounds__(256) void reduce_part_kernel(
    const float* __restrict__ kvpart, const float* __restrict__ kspart,
    float* __restrict__ kvb, float* __restrict__ ksum) {
    int i = blockIdx.x * 256 + threadIdx.x;
    if (i < 262144) {
        float s = 0.f;
#pragma unroll
        for (int c = 0; c < NCH; c++) s += kvpart[(size_t)c * 262144 + i];
        kvb[i] = s;
    } else if (i < 262144 + 4096) {
        int j = i - 262144;
        float s = 0.f;
#pragma unroll
        for (int c = 0; c < NCH; c++) s += kspart[(size_t)c * 4096 + j];
        ksum[j] = s;
    }
}

// ---------------------------------------------------------------------------
// MFMA combine: per (b,n), num = Q[256x64] @ kv[64x64], den via ksum column.
__global__ __launch_bounds__(256) void combine_kernel(
    const u16* __restrict__ qb, const float* __restrict__ kvb,
    const float* __restrict__ ksum, const float* __restrict__ g,
    const float* __restrict__ coeffp, u16* __restrict__ cmb) {
    int bn = blockIdx.x;
    int b = bn >> 4, n = bn & 15;
    __shared__ u16 qs[256 * 72];
    __shared__ u16 kvT[64 * 72];
    __shared__ u16 ksl[128];
    int tid = threadIdx.x;
    int s0 = blockIdx.y * 256;

    const u16* qsrc = qb + (size_t)bn * (S_ * 64) + (size_t)s0 * 64;
    for (int c = tid; c < 2048; c += 256) {
        int t = c >> 3, k8 = (c & 7) * 8;
        float4 tmp = *(const float4*)(qsrc + (size_t)c * 8);
        *(float4*)&qs[t * 72 + k8] = tmp;
    }
    for (int c = tid; c < 1024; c += 256) {
        int i = c >> 4, d4 = (c & 15) * 4;
        float4 kvv = *(const float4*)&kvb[(size_t)bn * 4096 + i * 64 + d4];
        kvT[(d4 + 0) * 72 + i] = f2bf(kvv.x);
        kvT[(d4 + 1) * 72 + i] = f2bf(kvv.y);
        kvT[(d4 + 2) * 72 + i] = f2bf(kvv.z);
        kvT[(d4 + 3) * 72 + i] = f2bf(kvv.w);
    }
    if (tid < 64)        ksl[tid] = f2bf(ksum[bn * 64 + tid]);
    else if (tid < 128)  ksl[tid] = 0;
    __syncthreads();

    int wave = tid >> 6, lane = tid & 63;
    int l15 = lane & 15, quad = lane >> 4;
    int wt = wave * 64;

    int ko0 = (l15 == 0) ? quad * 8      : 64;
    int ko1 = (l15 == 0) ? 32 + quad * 8 : 64;
    bf16x8 ksf0 = *(const bf16x8*)&ksl[ko0];
    bf16x8 ksf1 = *(const bf16x8*)&ksl[ko1];

    bf16x8 bfr0[4], bfr1[4];
#pragma unroll
    for (int nj = 0; nj < 4; nj++) {
        bfr0[nj] = *(const bf16x8*)&kvT[(nj * 16 + l15) * 72 + quad * 8];
        bfr1[nj] = *(const bf16x8*)&kvT[(nj * 16 + l15) * 72 + 32 + quad * 8];
    }

    f32x4 acc[4][4], dacc[4];
#pragma unroll
    for (int i = 0; i < 4; i++) {
        dacc[i] = {0.f, 0.f, 0.f, 0.f};
#pragma unroll
        for (int j = 0; j < 4; j++) acc[i][j] = {0.f, 0.f, 0.f, 0.f};
    }

#pragma unroll
    for (int mi = 0; mi < 4; mi++) {
        bf16x8 a0 = *(const bf16x8*)&qs[(wt + mi * 16 + l15) * 72 + quad * 8];
        bf16x8 a1 = *(const bf16x8*)&qs[(wt + mi * 16 + l15) * 72 + 32 + quad * 8];
        dacc[mi] = __builtin_amdgcn_mfma_f32_16x16x32_bf16(a0, ksf0, dacc[mi], 0, 0, 0);
        dacc[mi] = __builtin_amdgcn_mfma_f32_16x16x32_bf16(a1, ksf1, dacc[mi], 0, 0, 0);
#pragma unroll
        for (int nj = 0; nj < 4; nj++) {
            acc[mi][nj] = __builtin_amdgcn_mfma_f32_16x16x32_bf16(
                a0, bfr0[nj], acc[mi][nj], 0, 0, 0);
            acc[mi][nj] = __builtin_amdgcn_mfma_f32_16x16x32_bf16(
                a1, bfr1[nj], acc[mi][nj], 0, 0, 0);
        }
    }

    float coeff = *coeffp;
#pragma unroll
    for (int mi = 0; mi < 4; mi++) {
#pragma unroll
        for (int r = 0; r < 4; r++) {
            int s = s0 + wt + mi * 16 + quad * 4 + r;
            int t = b * S_ + s;
            float den = __shfl(dacc[mi][r], lane & 48) + 1e-6f;
            float gv = g[t];
            float w1 = gv / den + (1.f - gv) * coeff;
#pragma unroll
            for (int nj = 0; nj < 4; nj++) {
                int d = nj * 16 + l15;
                cmb[(size_t)t * H_ + n * 64 + d] = f2bf(acc[mi][nj][r] * w1);
            }
        }
    }
}

// ---------------------------------------------------------------------------
extern "C" void kernel_launch(void* const* d_in, const int* in_sizes, int n_in,
                              void* d_out, int out_size, void* d_ws, size_t ws_size,
                              hipStream_t stream) {
    const float* hs    = (const float*)d_in[0];
    const float* mask  = (const float*)d_in[1];
    const float* Wq    = (const float*)d_in[2];
    const float* bq    = (const float*)d_in[3];
    const float* Wk    = (const float*)d_in[4];
    const float* bk    = (const float*)d_in[5];
    const float* Wv    = (const float*)d_in[6];
    const float* bv    = (const float*)d_in[7];
    const float* Wo    = (const float*)d_in[8];
    const float* bo    = (const float*)d_in[9];
    const float* Wg    = (const float*)d_in[10];
    const float* bg    = (const float*)d_in[11];
    const float* decay = (const float*)d_in[12];
    const float* gate  = (const float*)d_in[13];
    float* out = (float*)d_out;

    // ---- workspace layout
    float* ws     = (float*)d_ws;
    float* kvb    = ws;                         // 262144
    float* ksum   = kvb + 262144;               // 4096
    float* gbuf   = ksum + 4096;                // 8192
    float* coeff  = gbuf + 8192;                // 64
    float* cosT   = coeff + 64;                 // 65536
    float* sinT   = cosT + 65536;               // 65536
    float* bqkv   = sinT + 65536;               // 3072 (+pad to 4096)
    float* kspart = bqkv + 4096;                // NCH*4096 = 65536
    float* kvpart = kspart + 65536;             // NCH*262144 = 4194304
    u16*   hsb    = (u16*)(kvpart + 4194304);   // T*1024
    u16*   Wt     = hsb + (size_t)T_ * H_;      // 4096*1024 ([Wq|Wk|Wv|Wo]^T)
    u16*   WoT    = Wt + (size_t)3072 * H_;
    u16*   qb     = Wt + (size_t)4096 * H_;     // T*1024 head-major
    u16*   kb     = qb + (size_t)T_ * H_;
    u16*   vb     = kb + (size_t)T_ * H_;
    u16*   cmb    = vb + (size_t)T_ * H_;

    prep_kernel<<<(S_ * 32 + 3072 + 256) / 256 + 1, 256, 0, stream>>>(
        decay, gate, coeff, cosT, sinT, bq, bk, bv, bqkv);
    cvt_gate_kernel<<<T_ / 8, 256, 0, stream>>>(hs, Wg, bg, hsb, gbuf);
    pack_w_kernel<<<dim3(16, 16, 4), 256, 0, stream>>>(Wq, Wk, Wv, Wo, Wt);

    gemm_qkv_kernel<<<dim3(3072 / 128, T_ / 64), 256, 0, stream>>>(
        hsb, Wt, bqkv, mask, cosT, sinT, qb, kb, vb);

    kv_part_kernel<<<dim3(B_ * NH, NCH), 256, 0, stream>>>(
        kb, vb, kvpart, kspart);
    reduce_part_kernel<<<(262144 + 4096 + 255) / 256, 256, 0, stream>>>(
        kvpart, kspart, kvb, ksum);

    combine_kernel<<<dim3(B_ * NH, S_ / 256), 256, 0, stream>>>(
        qb, kvb, ksum, gbuf, coeff, cmb);

    gemm_out_kernel<<<dim3(H_ / 128, T_ / 64), 256, 0, stream>>>(
        cmb, WoT, bo, out, H_);
}